// Round 1
// baseline (5182.992 us; speedup 1.0000x reference)
//
#include <hip/hip_runtime.h>
#include <math.h>

#define Bsz 64
#define Tn 64
#define Ln 100
#define Dn 128
#define An 18
#define Hn 512
#define G4n 2048

__device__ __forceinline__ float sigf(float x){ return 1.0f/(1.0f+expf(-x)); }

// ---------- demo transpose: demoT[l][d][b] = demo[0][b][l][d] ----------
__global__ __launch_bounds__(256) void demo_transpose_kernel(
    const float* __restrict__ demo, float* __restrict__ demoT)
{
  int idx = blockIdx.x*256 + threadIdx.x;           // total Ln*Dn*Bsz = 819200
  if (idx < Ln*Dn*Bsz) {
    int b = idx & 63;
    int d = (idx >> 6) & 127;
    int l = idx >> 13;
    demoT[idx] = demo[((size_t)(b*Ln + l))*Dn + d];
  }
}

// ---------- generic tiled GEMM: C[M][N] = A[M][K] * B[N][K]^T + bias[n] ----------
__global__ __launch_bounds__(256) void gemm_nt_kernel(
    const float* __restrict__ A, int lda,
    const float* __restrict__ B, int ldb,
    const float* __restrict__ bias,
    float* __restrict__ C, int ldc, int K)
{
  __shared__ float As[64][17];
  __shared__ float Bs[64][17];
  const int m0 = blockIdx.x * 64;
  const int n0 = blockIdx.y * 64;
  const int tx = threadIdx.x & 15;
  const int ty = threadIdx.x >> 4;
  float acc[4][4] = {};
  for (int k0 = 0; k0 < K; k0 += 16) {
    #pragma unroll
    for (int i = 0; i < 4; i++) {
      int e = threadIdx.x + i*256;
      int r = e >> 4, c = e & 15;
      As[r][c] = A[(size_t)(m0 + r)*lda + k0 + c];
      Bs[r][c] = B[(size_t)(n0 + r)*ldb + k0 + c];
    }
    __syncthreads();
    #pragma unroll
    for (int kk = 0; kk < 16; kk++) {
      float a0 = As[ty*4+0][kk], a1 = As[ty*4+1][kk], a2 = As[ty*4+2][kk], a3 = As[ty*4+3][kk];
      float b0 = Bs[tx*4+0][kk], b1 = Bs[tx*4+1][kk], b2 = Bs[tx*4+2][kk], b3 = Bs[tx*4+3][kk];
      acc[0][0] += a0*b0; acc[0][1] += a0*b1; acc[0][2] += a0*b2; acc[0][3] += a0*b3;
      acc[1][0] += a1*b0; acc[1][1] += a1*b1; acc[1][2] += a1*b2; acc[1][3] += a1*b3;
      acc[2][0] += a2*b0; acc[2][1] += a2*b1; acc[2][2] += a2*b2; acc[2][3] += a2*b3;
      acc[3][0] += a3*b0; acc[3][1] += a3*b1; acc[3][2] += a3*b2; acc[3][3] += a3*b3;
    }
    __syncthreads();
  }
  #pragma unroll
  for (int i = 0; i < 4; i++) {
    #pragma unroll
    for (int j = 0; j < 4; j++) {
      int n = n0 + tx*4 + j;
      float v = acc[i][j] + (bias ? bias[n] : 0.0f);
      C[(size_t)(m0 + ty*4 + i)*ldc + n] = v;
    }
  }
}

// ---------- encoder LSTM step: one block per h-column ----------
__global__ __launch_bounds__(256) void enc_step_kernel(
    const float* __restrict__ demoT,  // [Ln][Dn][Bsz]
    const float* __restrict__ hprev,  // [Hn][Bsz] (unused if l==0)
    float* __restrict__ hcur,         // [Hn][Bsz]
    float* __restrict__ cT,           // [Hn][Bsz] in-place
    float* __restrict__ enc,          // [Bsz][Ln][Hn]
    const float* __restrict__ Wih, const float* __restrict__ Whh,
    const float* __restrict__ bih, const float* __restrict__ bhh, int l)
{
  const int n = blockIdx.x;
  const int lane = threadIdx.x & 63;
  const int ks = threadIdx.x >> 6;
  const int r0 = n, r1 = Hn + n, r2 = 2*Hn + n, r3 = 3*Hn + n;
  float a0 = 0.f, a1 = 0.f, a2 = 0.f, a3 = 0.f;
  if (l > 0) {
    const float* w0 = Whh + (size_t)r0*Hn;
    const float* w1 = Whh + (size_t)r1*Hn;
    const float* w2 = Whh + (size_t)r2*Hn;
    const float* w3 = Whh + (size_t)r3*Hn;
    #pragma unroll 8
    for (int kk = 0; kk < Hn/4; kk++) {
      int k = ks*(Hn/4) + kk;
      float v = hprev[k*Bsz + lane];
      a0 += v*w0[k]; a1 += v*w1[k]; a2 += v*w2[k]; a3 += v*w3[k];
    }
  }
  {
    const float* w0 = Wih + (size_t)r0*Dn;
    const float* w1 = Wih + (size_t)r1*Dn;
    const float* w2 = Wih + (size_t)r2*Dn;
    const float* w3 = Wih + (size_t)r3*Dn;
    #pragma unroll 8
    for (int kk = 0; kk < Dn/4; kk++) {
      int k = ks*(Dn/4) + kk;
      float v = demoT[((size_t)l*Dn + k)*Bsz + lane];
      a0 += v*w0[k]; a1 += v*w1[k]; a2 += v*w2[k]; a3 += v*w3[k];
    }
  }
  __shared__ float red[4][4][Bsz];
  red[ks][0][lane] = a0; red[ks][1][lane] = a1;
  red[ks][2][lane] = a2; red[ks][3][lane] = a3;
  __syncthreads();
  if (threadIdx.x < Bsz) {
    int b = threadIdx.x;
    float g0 = red[0][0][b]+red[1][0][b]+red[2][0][b]+red[3][0][b] + bih[r0]+bhh[r0];
    float g1 = red[0][1][b]+red[1][1][b]+red[2][1][b]+red[3][1][b] + bih[r1]+bhh[r1];
    float g2 = red[0][2][b]+red[1][2][b]+red[2][2][b]+red[3][2][b] + bih[r2]+bhh[r2];
    float g3 = red[0][3][b]+red[1][3][b]+red[2][3][b]+red[3][3][b] + bih[r3]+bhh[r3];
    float ii = sigf(g0), ff = sigf(g1), gg = tanhf(g2), oo = sigf(g3);
    float c = (l > 0) ? cT[n*Bsz + b] : 0.0f;
    float cn = ff*c + ii*gg;
    float hn = oo*tanhf(cn);
    cT[n*Bsz + b] = cn;
    hcur[n*Bsz + b] = hn;
    enc[((size_t)b*Ln + l)*Hn + n] = hn;
  }
}

// ---------- decoder phase A: attention (blocks 0..63) + h-part gates (blocks 64..575) ----------
__global__ __launch_bounds__(256) void dec_attn_hpart_kernel(
    const float* __restrict__ hrow_prev,  // row-major [Bsz][Hn] (hhist[t-1] or h0)
    const float* __restrict__ hT_prev,    // [Hn][Bsz] (unused at t==0)
    const float* __restrict__ attnp,      // [Bsz*Ln][Hn]
    const float* __restrict__ enc,        // [Bsz][Ln][Hn]
    const int*   __restrict__ dlen,       // [Bsz]
    const float* __restrict__ Whh,        // lstm_Whh [4Hn][Hn]
    float* __restrict__ appT,             // [Hn][Bsz]
    float* __restrict__ hpart,            // [4Hn][Bsz]
    int t)
{
  __shared__ float hs[Hn];
  __shared__ float wls[128];
  __shared__ float mx_s, sum_s;
  __shared__ float red[4][4][Bsz];
  const int tid = threadIdx.x;
  if (blockIdx.x < Bsz) {
    const int b = blockIdx.x;
    for (int i = tid; i < Hn; i += 256) hs[i] = hrow_prev[(size_t)b*Hn + i];
    if (tid >= 200 && tid < 228) wls[tid - 100] = -1e30f;
    __syncthreads();
    const int len = dlen[b];
    if (tid < 200) {
      int l = tid >> 1, kh = tid & 1;
      const float* ap = attnp + ((size_t)(b*Ln + l))*Hn + kh*256;
      const float* hh = hs + kh*256;
      float s = 0.f;
      #pragma unroll 8
      for (int k = 0; k < 256; k++) s += ap[k]*hh[k];
      s += __shfl_xor(s, 1);
      if (kh == 0) wls[l] = (l < len) ? s*0.1f : -1e30f;
    }
    __syncthreads();
    if (tid < 64) {
      float v = fmaxf(wls[tid], wls[tid+64]);
      for (int off = 1; off < 64; off <<= 1) v = fmaxf(v, __shfl_xor(v, off));
      if (tid == 0) mx_s = v;
    }
    __syncthreads();
    float mx = mx_s;
    if (tid < 64) {
      float e0 = (wls[tid]      > -1e29f) ? expf(wls[tid]      - mx) : 0.f;
      float e1 = (wls[tid+64]   > -1e29f) ? expf(wls[tid+64]   - mx) : 0.f;
      wls[tid] = e0; wls[tid+64] = e1;
      float v = e0 + e1;
      for (int off = 1; off < 64; off <<= 1) v += __shfl_xor(v, off);
      if (tid == 0) sum_s = v;
    }
    __syncthreads();
    float inv = 1.0f / sum_s;
    for (int c2 = 0; c2 < 2; c2++) {
      int hc = tid + c2*256;
      const float* eb = enc + (size_t)b*Ln*Hn + hc;
      float a = 0.f;
      for (int l2 = 0; l2 < len; ++l2) a += wls[l2]*eb[(size_t)l2*Hn];
      appT[hc*Bsz + b] = a*inv;
    }
  } else {
    const int n = blockIdx.x - Bsz;
    const int lane = tid & 63;
    const int ks = tid >> 6;
    const int r0 = n, r1 = Hn + n, r2 = 2*Hn + n, r3 = 3*Hn + n;
    const float* w0 = Whh + (size_t)r0*Hn;
    const float* w1 = Whh + (size_t)r1*Hn;
    const float* w2 = Whh + (size_t)r2*Hn;
    const float* w3 = Whh + (size_t)r3*Hn;
    float a0 = 0.f, a1 = 0.f, a2 = 0.f, a3 = 0.f;
    if (t == 0) {
      #pragma unroll 8
      for (int kk = 0; kk < Hn/4; kk++) {
        int k = ks*(Hn/4) + kk;
        float v = hrow_prev[(size_t)lane*Hn + k];
        a0 += v*w0[k]; a1 += v*w1[k]; a2 += v*w2[k]; a3 += v*w3[k];
      }
    } else {
      #pragma unroll 8
      for (int kk = 0; kk < Hn/4; kk++) {
        int k = ks*(Hn/4) + kk;
        float v = hT_prev[k*Bsz + lane];
        a0 += v*w0[k]; a1 += v*w1[k]; a2 += v*w2[k]; a3 += v*w3[k];
      }
    }
    red[ks][0][lane] = a0; red[ks][1][lane] = a1;
    red[ks][2][lane] = a2; red[ks][3][lane] = a3;
    __syncthreads();
    if (tid < Bsz) {
      int b = tid;
      hpart[(size_t)r0*Bsz + b] = red[0][0][b]+red[1][0][b]+red[2][0][b]+red[3][0][b];
      hpart[(size_t)r1*Bsz + b] = red[0][1][b]+red[1][1][b]+red[2][1][b]+red[3][1][b];
      hpart[(size_t)r2*Bsz + b] = red[0][2][b]+red[1][2][b]+red[2][2][b]+red[3][2][b];
      hpart[(size_t)r3*Bsz + b] = red[0][3][b]+red[1][3][b]+red[2][3][b]+red[3][3][b];
    }
  }
}

// ---------- decoder phase B: x = relu(applied @ Wa^T + preobs + comb_b) ----------
__global__ __launch_bounds__(256) void dec_x_kernel(
    const float* __restrict__ appT,   // [Hn][Bsz]
    const float* __restrict__ preobs, // [Tn*Bsz][Hn]
    const float* __restrict__ comb_W, const float* __restrict__ comb_b,
    float* __restrict__ xT, int t)
{
  const int n = blockIdx.x;
  const int lane = threadIdx.x & 63;
  const int ks = threadIdx.x >> 6;
  const float* w = comb_W + (size_t)n*(Hn + Dn);
  float a = 0.f;
  #pragma unroll 8
  for (int kk = 0; kk < Hn/4; kk++) {
    int k = ks*(Hn/4) + kk;
    a += appT[k*Bsz + lane]*w[k];
  }
  __shared__ float red[4][Bsz];
  red[ks][lane] = a;
  __syncthreads();
  if (threadIdx.x < Bsz) {
    int b = threadIdx.x;
    float v = red[0][b]+red[1][b]+red[2][b]+red[3][b];
    v += preobs[((size_t)(t*Bsz + b))*Hn + n] + comb_b[n];
    xT[n*Bsz + b] = fmaxf(v, 0.f);
  }
}

// ---------- decoder phase C: gates = x@Wih^T + hpart + bias; cell update ----------
__global__ __launch_bounds__(256) void dec_cell_kernel(
    const float* __restrict__ xT,     // [Hn][Bsz]
    const float* __restrict__ hpart,  // [4Hn][Bsz]
    const float* __restrict__ Wih,    // lstm_Wih
    const float* __restrict__ bih, const float* __restrict__ bhh,
    const float* __restrict__ c0,
    float* __restrict__ cT, float* __restrict__ hTcur,
    float* __restrict__ hhist, int t)
{
  const int n = blockIdx.x;
  const int lane = threadIdx.x & 63;
  const int ks = threadIdx.x >> 6;
  const int r0 = n, r1 = Hn + n, r2 = 2*Hn + n, r3 = 3*Hn + n;
  const float* w0 = Wih + (size_t)r0*Hn;
  const float* w1 = Wih + (size_t)r1*Hn;
  const float* w2 = Wih + (size_t)r2*Hn;
  const float* w3 = Wih + (size_t)r3*Hn;
  float a0 = 0.f, a1 = 0.f, a2 = 0.f, a3 = 0.f;
  #pragma unroll 8
  for (int kk = 0; kk < Hn/4; kk++) {
    int k = ks*(Hn/4) + kk;
    float v = xT[k*Bsz + lane];
    a0 += v*w0[k]; a1 += v*w1[k]; a2 += v*w2[k]; a3 += v*w3[k];
  }
  __shared__ float red[4][4][Bsz];
  red[ks][0][lane] = a0; red[ks][1][lane] = a1;
  red[ks][2][lane] = a2; red[ks][3][lane] = a3;
  __syncthreads();
  if (threadIdx.x < Bsz) {
    int b = threadIdx.x;
    float g0 = red[0][0][b]+red[1][0][b]+red[2][0][b]+red[3][0][b] + hpart[(size_t)r0*Bsz+b] + bih[r0]+bhh[r0];
    float g1 = red[0][1][b]+red[1][1][b]+red[2][1][b]+red[3][1][b] + hpart[(size_t)r1*Bsz+b] + bih[r1]+bhh[r1];
    float g2 = red[0][2][b]+red[1][2][b]+red[2][2][b]+red[3][2][b] + hpart[(size_t)r2*Bsz+b] + bih[r2]+bhh[r2];
    float g3 = red[0][3][b]+red[1][3][b]+red[2][3][b]+red[3][3][b] + hpart[(size_t)r3*Bsz+b] + bih[r3]+bhh[r3];
    float ii = sigf(g0), ff = sigf(g1), gg = tanhf(g2), oo = sigf(g3);
    float c = (t > 0) ? cT[n*Bsz + b] : c0[(size_t)b*Hn + n];
    float cn = ff*c + ii*gg;
    float hn = oo*tanhf(cn);
    cT[n*Bsz + b] = cn;
    hTcur[n*Bsz + b] = hn;
    hhist[((size_t)(t*Bsz + b))*Hn + n] = hn;
  }
}

// ---------- q head: q[t][b][a] = m[t*B+b] . out_W[a] + out_b[a] ----------
__global__ __launch_bounds__(256) void qout_kernel(
    const float* __restrict__ m, const float* __restrict__ out_W,
    const float* __restrict__ out_b, float* __restrict__ q)
{
  const int t = blockIdx.x;
  for (int p = threadIdx.x; p < Bsz*An; p += 256) {
    int b = p / An, a2 = p % An;
    const float* mr = m + ((size_t)(t*Bsz + b))*Hn;
    const float* wr = out_W + (size_t)a2*Hn;
    float s = out_b[a2];
    #pragma unroll 8
    for (int k = 0; k < Hn; k++) s += mr[k]*wr[k];
    q[((size_t)(t*Bsz + b))*An + a2] = s;
  }
}

// ---------- final h,c copy into d_out ----------
__global__ __launch_bounds__(256) void final_hc_kernel(
    const float* __restrict__ hhist, const float* __restrict__ cT,
    float* __restrict__ out)
{
  int idx = blockIdx.x*256 + threadIdx.x;
  if (idx < Bsz*Hn) {
    int b = idx / Hn, n = idx % Hn;
    out[Tn*Bsz*An + idx]           = hhist[((size_t)((Tn-1)*Bsz + b))*Hn + n];
    out[Tn*Bsz*An + Bsz*Hn + idx]  = cT[n*Bsz + b];
  }
}

extern "C" void kernel_launch(void* const* d_in, const int* in_sizes, int n_in,
                              void* d_out, int out_size, void* d_ws, size_t ws_size,
                              hipStream_t stream) {
  (void)in_sizes; (void)n_in; (void)out_size; (void)ws_size;
  const float* state    = (const float*)d_in[0];
  const float* demo     = (const float*)d_in[1];
  const int*   dlen     = (const int*)  d_in[2];
  const float* h0       = (const float*)d_in[5];
  const float* c0       = (const float*)d_in[6];
  const float* enc_Wih  = (const float*)d_in[7];
  const float* enc_Whh  = (const float*)d_in[8];
  const float* enc_bih  = (const float*)d_in[9];
  const float* enc_bhh  = (const float*)d_in[10];
  const float* attn_W   = (const float*)d_in[11];
  const float* attn_b   = (const float*)d_in[12];
  const float* comb_W   = (const float*)d_in[13];
  const float* comb_b   = (const float*)d_in[14];
  const float* lstm_Wih = (const float*)d_in[15];
  const float* lstm_Whh = (const float*)d_in[16];
  const float* lstm_bih = (const float*)d_in[17];
  const float* lstm_bhh = (const float*)d_in[18];
  const float* mid_W    = (const float*)d_in[19];
  const float* mid_b    = (const float*)d_in[20];
  const float* out_W    = (const float*)d_in[21];
  const float* out_b    = (const float*)d_in[22];
  float* ws = (float*)d_ws;
  float* qout = (float*)d_out;

  // workspace layout (floats)
  float* demoT  = ws + 0;          // 819200
  float* henc   = ws + 819200;     // 2*32768
  float* cencT  = ws + 884736;     // 32768
  float* enc    = ws + 917504;     // 3276800
  float* attnp  = ws + 4194304;    // 3276800
  float* preobs = ws + 7471104;    // 2097152
  float* hT     = ws + 9568256;    // 2*32768
  float* cT     = ws + 9633792;    // 32768
  float* xT     = ws + 9666560;    // 32768
  float* appT   = ws + 9699328;    // 32768
  float* hpart  = ws + 9732096;    // 131072
  float* hhist  = ws + 9863168;    // 2097152
  float* mbuf   = enc;             // alias: enc dead after decoder, mbuf needs 2097152 <= 3276800

  demo_transpose_kernel<<<3200, 256, 0, stream>>>(demo, demoT);

  // preobs = state @ Wo^T  (Wo = comb_W[:, 512:640]), no bias (comb_b added in dec_x)
  gemm_nt_kernel<<<dim3(Tn*Bsz/64, Hn/64), 256, 0, stream>>>(
      state, Dn, comb_W + Hn, Hn + Dn, nullptr, preobs, Hn, Dn);

  // encoder scan
  for (int l = 0; l < Ln; l++) {
    const float* hprev = henc + ((l + 1) & 1) * (Hn*Bsz);
    float* hcur        = henc + (l & 1) * (Hn*Bsz);
    enc_step_kernel<<<Hn, 256, 0, stream>>>(
        demoT, hprev, hcur, cencT, enc, enc_Wih, enc_Whh, enc_bih, enc_bhh, l);
  }

  // attn_proj = enc @ attn_W^T + attn_b
  gemm_nt_kernel<<<dim3(Bsz*Ln/64, Hn/64), 256, 0, stream>>>(
      enc, Hn, attn_W, Hn, attn_b, attnp, Hn, Hn);

  // decoder scan
  for (int t = 0; t < Tn; t++) {
    const float* hrow_prev = (t == 0) ? h0 : (hhist + (size_t)(t-1)*Bsz*Hn);
    const float* hT_prev   = hT + ((t + 1) & 1) * (Hn*Bsz);
    float* hT_cur          = hT + (t & 1) * (Hn*Bsz);
    dec_attn_hpart_kernel<<<Bsz + Hn, 256, 0, stream>>>(
        hrow_prev, hT_prev, attnp, enc, dlen, lstm_Whh, appT, hpart, t);
    dec_x_kernel<<<Hn, 256, 0, stream>>>(appT, preobs, comb_W, comb_b, xT, t);
    dec_cell_kernel<<<Hn, 256, 0, stream>>>(
        xT, hpart, lstm_Wih, lstm_bih, lstm_bhh, c0, cT, hT_cur, hhist, t);
  }

  // m = hhist @ mid_W^T + mid_b  (into aliased enc buffer)
  gemm_nt_kernel<<<dim3(Tn*Bsz/64, Hn/64), 256, 0, stream>>>(
      hhist, Hn, mid_W, Hn, mid_b, mbuf, Hn, Hn);

  qout_kernel<<<Tn, 256, 0, stream>>>(mbuf, out_W, out_b, qout);
  final_hc_kernel<<<Bsz*Hn/256, 256, 0, stream>>>(hhist, cT, qout);
}